// Round 1
// baseline (256.273 us; speedup 1.0000x reference)
//
#include <hip/hip_runtime.h>

// LSTMModel autonomous scalar recurrence.
// HIDDEN=128, IN_DIM=OUT_DIM=1, T=512, BATCH=512.
// Reference collapses to: per batch element b, s = x[0,b,0]; repeat 512x:
//   i_k = s*Wi_k + bi_k ; g_k = s*Wg_k + bg_k ; o_k = s*Wo_k + bo_k   (f gate dead: c0=0)
//   c_k = sigmoid(i_k)*tanh(g_k) ; h_k = sigmoid(o_k)*tanh(c_k)
//   p = sum_k relu(h_k)*fc_w[k] + fc_b ;  out[t,b] = p ; s = p
// One wave per chain (lane handles k and k+64); butterfly shfl_xor reduction
// leaves the sum in every lane so the feedback needs no broadcast.

#define HIDDEN  128
#define T_STEPS 512
#define BATCH   512

__device__ __forceinline__ float fast_rcp(float x) {
    return __builtin_amdgcn_rcpf(x);        // v_rcp_f32, ~1 ulp
}
__device__ __forceinline__ float fast_exp(float x) {
    return __expf(x);                       // v_exp_f32 path
}
__device__ __forceinline__ float sigmoid_f(float x) {
    return fast_rcp(1.0f + fast_exp(-x));   // stable both directions
}
__device__ __forceinline__ float tanh_f(float x) {
    // tanh(x) = 1 - 2/(e^{2x}+1); stable for x -> +/-inf
    return 1.0f - 2.0f * fast_rcp(1.0f + fast_exp(2.0f * x));
}

__global__ __launch_bounds__(64)
void lstm_auto_kernel(const float* __restrict__ x,
                      const float* __restrict__ W_ih,
                      const float* __restrict__ b_ih,
                      const float* __restrict__ b_hh,
                      const float* __restrict__ fc_w,
                      const float* __restrict__ fc_b,
                      float* __restrict__ out)
{
    const int lane = threadIdx.x;    // 0..63
    const int b    = blockIdx.x;     // chain (batch element)
    const int k0 = lane;
    const int k1 = lane + 64;

    // gate row blocks in the 4H dimension: i:[0,128) f:[128,256) g:[256,384) o:[384,512)
    const float wi0 = W_ih[k0],        wi1 = W_ih[k1];
    const float wg0 = W_ih[256 + k0],  wg1 = W_ih[256 + k1];
    const float wo0 = W_ih[384 + k0],  wo1 = W_ih[384 + k1];
    const float bi0 = b_ih[k0]       + b_hh[k0];
    const float bi1 = b_ih[k1]       + b_hh[k1];
    const float bg0 = b_ih[256 + k0] + b_hh[256 + k0];
    const float bg1 = b_ih[256 + k1] + b_hh[256 + k1];
    const float bo0 = b_ih[384 + k0] + b_hh[384 + k0];
    const float bo1 = b_ih[384 + k1] + b_hh[384 + k1];
    const float fw0 = fc_w[k0],        fw1 = fc_w[k1];
    const float fcb = fc_b[0];

    float s = x[b];   // x[0, b, 0]; x[1:] is never consumed (autonomous mode)

    for (int t = 0; t < T_STEPS; ++t) {
        const float iv0 = fmaf(s, wi0, bi0), iv1 = fmaf(s, wi1, bi1);
        const float gv0 = fmaf(s, wg0, bg0), gv1 = fmaf(s, wg1, bg1);
        const float ov0 = fmaf(s, wo0, bo0), ov1 = fmaf(s, wo1, bo1);

        const float c0 = sigmoid_f(iv0) * tanh_f(gv0);
        const float c1 = sigmoid_f(iv1) * tanh_f(gv1);
        const float h0 = sigmoid_f(ov0) * tanh_f(c0);
        const float h1 = sigmoid_f(ov1) * tanh_f(c1);

        float r = fmaxf(h0, 0.0f) * fw0 + fmaxf(h1, 0.0f) * fw1;

        // full-wave butterfly: every lane ends with the 128-term sum
        #pragma unroll
        for (int m = 1; m < 64; m <<= 1)
            r += __shfl_xor(r, m, 64);

        const float p = r + fcb;
        if (lane == 0) out[t * BATCH + b] = p;   // fire-and-forget store
        s = p;                                   // feedback (uniform across lanes)
    }
}

extern "C" void kernel_launch(void* const* d_in, const int* in_sizes, int n_in,
                              void* d_out, int out_size, void* d_ws, size_t ws_size,
                              hipStream_t stream) {
    const float* x    = (const float*)d_in[0];   // (T, BATCH, 1)
    const float* W_ih = (const float*)d_in[1];   // (512, 1)
    // d_in[2] = W_hh — provably unused (h0 = 0)
    const float* b_ih = (const float*)d_in[3];   // (512,)
    const float* b_hh = (const float*)d_in[4];   // (512,)
    const float* fc_w = (const float*)d_in[5];   // (1, 128)
    const float* fc_b = (const float*)d_in[6];   // (1,)
    float* out = (float*)d_out;                  // (T, BATCH) fp32

    lstm_auto_kernel<<<BATCH, 64, 0, stream>>>(x, W_ih, b_ih, b_hh, fc_w, fc_b, out);
}

// Round 2
// 68.903 us; speedup vs baseline: 3.7193x; 3.7193x over previous
//
#include <hip/hip_runtime.h>

// LSTMModel autonomous scalar recurrence.
// HIDDEN=128, IN_DIM=OUT_DIM=1, T=512, BATCH=512.
// Per batch element b: s = x[0,b,0]; repeat 512x:
//   i_k = s*Wi_k + bi_k ; g_k = s*Wg_k + bg_k ; o_k = s*Wo_k + bo_k   (f gate dead: c0=0)
//   c_k = sigmoid(i_k)*tanh(g_k) ; h_k = sigmoid(o_k)*tanh(c_k)
//   p = sum_k relu(h_k)*fc_w[k] + fc_b ;  out[t,b] = p ; s = p
//
// R1 post-mortem: 920 cyc/step, dominated by 6 dependent __shfl_xor on the
// LDS pipe (~120 cyc each). Fix 1: DPP reduction on the VALU pipe (~5 cyc/stage).
// Fix 2: the map is contractive and batch-independent; once p_{t+1}==p_t
// bitwise, all later outputs are identical -> early-exit + constant fill
// (exact, deterministic, falls back to full loop).

#define HIDDEN  128
#define T_STEPS 512
#define BATCH   512

__device__ __forceinline__ float fast_rcp(float x) { return __builtin_amdgcn_rcpf(x); }
__device__ __forceinline__ float sigmoid_f(float x) {
    return fast_rcp(1.0f + __expf(-x));
}
__device__ __forceinline__ float tanh_f(float x) {
    // tanh(x) = 1 - 2/(e^{2x}+1); stable for x -> +/-inf
    return 1.0f - 2.0f * fast_rcp(1.0f + __expf(2.0f * x));
}

// r += dpp_mov(r, ctrl); bound_ctrl=1 -> invalid source lanes contribute 0.
template <int CTRL>
__device__ __forceinline__ float dpp_add(float x) {
    int y = __builtin_amdgcn_update_dpp(0, __float_as_int(x), CTRL, 0xF, 0xF, true);
    return x + __int_as_float(y);
}

// Full wave64 sum; returns total as a wave-uniform (SGPR) value.
__device__ __forceinline__ float wave_sum64(float r) {
    r = dpp_add<0xB1>(r);   // quad_perm [1,0,3,2]  (xor 1)
    r = dpp_add<0x4E>(r);   // quad_perm [2,3,0,1]  (xor 2)
    r = dpp_add<0x141>(r);  // row_half_mirror      (xor 4)
    r = dpp_add<0x140>(r);  // row_mirror           (xor 8)
    r = dpp_add<0x142>(r);  // row_bcast15: row r reads lane 16r-1
    r = dpp_add<0x143>(r);  // row_bcast31: rows 2,3 read lane 31 -> lane 63 = total
    return __int_as_float(__builtin_amdgcn_readlane(__float_as_int(r), 63));
}

__global__ __launch_bounds__(64)
void lstm_auto_kernel(const float* __restrict__ x,
                      const float* __restrict__ W_ih,
                      const float* __restrict__ b_ih,
                      const float* __restrict__ b_hh,
                      const float* __restrict__ fc_w,
                      const float* __restrict__ fc_b,
                      float* __restrict__ out)
{
    const int lane = threadIdx.x;    // 0..63
    const int b    = blockIdx.x;     // chain (batch element)
    const int k0 = lane;
    const int k1 = lane + 64;

    // gate rows in 4H: i:[0,128) f:[128,256) g:[256,384) o:[384,512)
    const float wi0 = W_ih[k0],        wi1 = W_ih[k1];
    const float wg0 = W_ih[256 + k0],  wg1 = W_ih[256 + k1];
    const float wo0 = W_ih[384 + k0],  wo1 = W_ih[384 + k1];
    const float bi0 = b_ih[k0]       + b_hh[k0];
    const float bi1 = b_ih[k1]       + b_hh[k1];
    const float bg0 = b_ih[256 + k0] + b_hh[256 + k0];
    const float bg1 = b_ih[256 + k1] + b_hh[256 + k1];
    const float bo0 = b_ih[384 + k0] + b_hh[384 + k0];
    const float bo1 = b_ih[384 + k1] + b_hh[384 + k1];
    const float fw0 = fc_w[k0],        fw1 = fc_w[k1];
    const float fcb = fc_b[0];

    float s = x[b];                        // x[0, b, 0]; autonomous mode
    int   s_prev_bits = 0x7fc00000;        // NaN bits: never equals a real p
    int   t = 0;

    for (; t < T_STEPS; ++t) {
        const float iv0 = fmaf(s, wi0, bi0), iv1 = fmaf(s, wi1, bi1);
        const float gv0 = fmaf(s, wg0, bg0), gv1 = fmaf(s, wg1, bg1);
        const float ov0 = fmaf(s, wo0, bo0), ov1 = fmaf(s, wo1, bo1);

        const float c0 = sigmoid_f(iv0) * tanh_f(gv0);
        const float c1 = sigmoid_f(iv1) * tanh_f(gv1);
        const float h0 = sigmoid_f(ov0) * tanh_f(c0);
        const float h1 = sigmoid_f(ov1) * tanh_f(c1);

        const float r = fmaxf(h0, 0.0f) * fw0 + fmaxf(h1, 0.0f) * fw1;

        const float p = wave_sum64(r) + fcb;   // wave-uniform
        if (lane == 0) out[t * BATCH + b] = p;

        const int p_bits = __float_as_int(p);
        s = p;
        if (p_bits == s_prev_bits) break;      // bitwise fixed point: all later
        s_prev_bits = p_bits;                  // outputs are identical
    }

    // Constant-fill the remaining timesteps (exact: p is the fixed point).
    if (t < T_STEPS - 1) {
        for (int tf = t + 1 + lane; tf < T_STEPS; tf += 64)
            out[tf * BATCH + b] = s;
    }
}

extern "C" void kernel_launch(void* const* d_in, const int* in_sizes, int n_in,
                              void* d_out, int out_size, void* d_ws, size_t ws_size,
                              hipStream_t stream) {
    const float* x    = (const float*)d_in[0];   // (T, BATCH, 1)
    const float* W_ih = (const float*)d_in[1];   // (512, 1)
    // d_in[2] = W_hh — provably unused (h0 = 0)
    const float* b_ih = (const float*)d_in[3];   // (512,)
    const float* b_hh = (const float*)d_in[4];   // (512,)
    const float* fc_w = (const float*)d_in[5];   // (1, 128)
    const float* fc_b = (const float*)d_in[6];   // (1,)
    float* out = (float*)d_out;                  // (T, BATCH) fp32

    lstm_auto_kernel<<<BATCH, 64, 0, stream>>>(x, W_ih, b_ih, b_hh, fc_w, fc_b, out);
}

// Round 3
// 67.863 us; speedup vs baseline: 3.7763x; 1.0153x over previous
//
#include <hip/hip_runtime.h>

// LSTMModel autonomous scalar recurrence.
// HIDDEN=128, IN_DIM=OUT_DIM=1, T=512, BATCH=512.
// Per batch element b: s = x[0,b,0]; repeat 512x:
//   i_k = s*Wi_k + bi_k ; g_k = s*Wg_k + bg_k ; o_k = s*Wo_k + bo_k   (f gate dead: c0=0)
//   c_k = sigmoid(i_k)*tanh(g_k) ; h_k = sigmoid(o_k)*tanh(c_k)
//   p = sum_k relu(h_k)*fc_w[k] + fc_b ;  out[t,b] = p ; s = p
//
// R1: 920 cyc/step — 6 dependent __shfl_xor on the LDS pipe. -> DPP reduction.
// R2: bitwise fixed-point early exit works (absmax 0.0); remaining kernel time
//     is the column-strided tail fill (stride-2048B stores, ~250K 64B txns).
// R3: two-kernel split — chain kernel records (t_start, p_star) per column in
//     d_ws; a second coalesced kernel writes the constant tail row-major.
//     Chain math is bit-identical to R2.

#define HIDDEN  128
#define T_STEPS 512
#define BATCH   512

__device__ __forceinline__ float fast_rcp(float x) { return __builtin_amdgcn_rcpf(x); }
__device__ __forceinline__ float sigmoid_f(float x) {
    return fast_rcp(1.0f + __expf(-x));
}
__device__ __forceinline__ float tanh_f(float x) {
    // tanh(x) = 1 - 2/(e^{2x}+1); stable for x -> +/-inf
    return 1.0f - 2.0f * fast_rcp(1.0f + __expf(2.0f * x));
}

// r += dpp_mov(r, ctrl); bound_ctrl=1 -> invalid source lanes contribute 0.
template <int CTRL>
__device__ __forceinline__ float dpp_add(float x) {
    int y = __builtin_amdgcn_update_dpp(0, __float_as_int(x), CTRL, 0xF, 0xF, true);
    return x + __int_as_float(y);
}

// Full wave64 sum on the VALU pipe; returns total as a wave-uniform value.
__device__ __forceinline__ float wave_sum64(float r) {
    r = dpp_add<0xB1>(r);   // quad_perm [1,0,3,2]  (xor 1)
    r = dpp_add<0x4E>(r);   // quad_perm [2,3,0,1]  (xor 2)
    r = dpp_add<0x141>(r);  // row_half_mirror      (xor 4)
    r = dpp_add<0x140>(r);  // row_mirror           (xor 8)
    r = dpp_add<0x142>(r);  // row_bcast15
    r = dpp_add<0x143>(r);  // row_bcast31 -> lane 63 holds the total
    return __int_as_float(__builtin_amdgcn_readlane(__float_as_int(r), 63));
}

__global__ __launch_bounds__(64)
void lstm_chain_kernel(const float* __restrict__ x,
                       const float* __restrict__ W_ih,
                       const float* __restrict__ b_ih,
                       const float* __restrict__ b_hh,
                       const float* __restrict__ fc_w,
                       const float* __restrict__ fc_b,
                       float* __restrict__ out,
                       int*   __restrict__ t_start,
                       float* __restrict__ p_star)
{
    const int lane = threadIdx.x;    // 0..63
    const int b    = blockIdx.x;     // chain (batch element)
    const int k0 = lane;
    const int k1 = lane + 64;

    // gate rows in 4H: i:[0,128) f:[128,256) g:[256,384) o:[384,512)
    const float wi0 = W_ih[k0],        wi1 = W_ih[k1];
    const float wg0 = W_ih[256 + k0],  wg1 = W_ih[256 + k1];
    const float wo0 = W_ih[384 + k0],  wo1 = W_ih[384 + k1];
    const float bi0 = b_ih[k0]       + b_hh[k0];
    const float bi1 = b_ih[k1]       + b_hh[k1];
    const float bg0 = b_ih[256 + k0] + b_hh[256 + k0];
    const float bg1 = b_ih[256 + k1] + b_hh[256 + k1];
    const float bo0 = b_ih[384 + k0] + b_hh[384 + k0];
    const float bo1 = b_ih[384 + k1] + b_hh[384 + k1];
    const float fw0 = fc_w[k0],        fw1 = fc_w[k1];
    const float fcb = fc_b[0];

    float s = x[b];                        // x[0, b, 0]; autonomous mode
    int   s_prev_bits = 0x7fc00000;        // NaN bits: never equals a real p
    int   t = 0;

    for (; t < T_STEPS; ++t) {
        const float iv0 = fmaf(s, wi0, bi0), iv1 = fmaf(s, wi1, bi1);
        const float gv0 = fmaf(s, wg0, bg0), gv1 = fmaf(s, wg1, bg1);
        const float ov0 = fmaf(s, wo0, bo0), ov1 = fmaf(s, wo1, bo1);

        const float c0 = sigmoid_f(iv0) * tanh_f(gv0);
        const float c1 = sigmoid_f(iv1) * tanh_f(gv1);
        const float h0 = sigmoid_f(ov0) * tanh_f(c0);
        const float h1 = sigmoid_f(ov1) * tanh_f(c1);

        const float r = fmaxf(h0, 0.0f) * fw0 + fmaxf(h1, 0.0f) * fw1;

        const float p = wave_sum64(r) + fcb;   // wave-uniform
        if (lane == 0) out[t * BATCH + b] = p;

        const int p_bits = __float_as_int(p);
        s = p;
        if (p_bits == s_prev_bits) break;      // bitwise fixed point reached
        s_prev_bits = p_bits;
    }

    if (lane == 0) {
        // Converged at step t: rows 0..t are written; rows t+1.. are s forever.
        t_start[b] = (t < T_STEPS) ? (t + 1) : T_STEPS;
        p_star[b]  = s;
    }
}

// Coalesced constant tail fill: thread n -> (t = n>>9, b = n&511).
__global__ __launch_bounds__(256)
void tail_fill_kernel(const int*   __restrict__ t_start,
                      const float* __restrict__ p_star,
                      float* __restrict__ out)
{
    const int n = blockIdx.x * 256 + threadIdx.x;   // 0 .. T*BATCH-1
    const int b = n & (BATCH - 1);
    const int t = n >> 9;
    if (t >= t_start[b]) out[n] = p_star[b];
}

extern "C" void kernel_launch(void* const* d_in, const int* in_sizes, int n_in,
                              void* d_out, int out_size, void* d_ws, size_t ws_size,
                              hipStream_t stream) {
    const float* x    = (const float*)d_in[0];   // (T, BATCH, 1)
    const float* W_ih = (const float*)d_in[1];   // (512, 1)
    // d_in[2] = W_hh — provably unused (h0 = 0)
    const float* b_ih = (const float*)d_in[3];   // (512,)
    const float* b_hh = (const float*)d_in[4];   // (512,)
    const float* fc_w = (const float*)d_in[5];   // (1, 128)
    const float* fc_b = (const float*)d_in[6];   // (1,)
    float* out = (float*)d_out;                  // (T, BATCH) fp32

    int*   t_start = (int*)d_ws;                 // 512 ints
    float* p_star  = (float*)d_ws + BATCH;       // 512 floats

    lstm_chain_kernel<<<BATCH, 64, 0, stream>>>(x, W_ih, b_ih, b_hh, fc_w, fc_b,
                                                out, t_start, p_star);
    tail_fill_kernel<<<(T_STEPS * BATCH) / 256, 256, 0, stream>>>(t_start, p_star, out);
}

// Round 4
// 67.581 us; speedup vs baseline: 3.7921x; 1.0042x over previous
//
#include <hip/hip_runtime.h>

// LSTMModel autonomous scalar recurrence.
// HIDDEN=128, IN_DIM=OUT_DIM=1, T=512, BATCH=512.
// Per batch element b: s = x[0,b,0]; repeat 512x:
//   i_k = s*Wi_k + bi_k ; g_k = s*Wg_k + bg_k ; o_k = s*Wo_k + bo_k   (f gate dead: c0=0)
//   c_k = sigmoid(i_k)*tanh(g_k) ; h_k = sigmoid(o_k)*tanh(c_k)
//   p = sum_k relu(h_k)*fc_w[k] + fc_b ;  out[t,b] = p ; s = p
//
// R1: 920 cyc/step — 6 dependent __shfl_xor on LDS pipe -> DPP reduction (R2).
// R2: bitwise fixed-point early exit (contractive map, |F'|~0.02) -> ~10 µs kernel.
// R3: split tail-fill kernel: only -1 µs. Remaining ~8.6 µs is dispatch overhead
//     (2 launches + cross-kernel d_ws dependency), not memory.
// R4: single fused dispatch. 64 blocks x 512 threads = 8 chains/block; results
//     shared via LDS; block-cooperative coalesced tail fill (8-wide segments).
//     Critical-path trims: log2e folded into pre-scaled weights (v_exp_f32 is
//     exp2), fc_b folded into lane 0's partial before the butterfly.

#define HIDDEN  128
#define T_STEPS 512
#define BATCH   512
#define CH_PER_BLK 8          // chains (waves) per block
#define NBLK (BATCH / CH_PER_BLK)

__device__ __forceinline__ float fast_rcp(float x)  { return __builtin_amdgcn_rcpf(x); }
__device__ __forceinline__ float fast_exp2(float x) { return __builtin_amdgcn_exp2f(x); }

// r += dpp_mov(r, ctrl); bound_ctrl=1 -> invalid source lanes contribute 0.
template <int CTRL>
__device__ __forceinline__ float dpp_add(float x) {
    int y = __builtin_amdgcn_update_dpp(0, __float_as_int(x), CTRL, 0xF, 0xF, true);
    return x + __int_as_float(y);
}

// Full wave64 sum on the VALU pipe; returns total as a wave-uniform value.
__device__ __forceinline__ float wave_sum64(float r) {
    r = dpp_add<0xB1>(r);   // quad_perm [1,0,3,2]  (xor 1)
    r = dpp_add<0x4E>(r);   // quad_perm [2,3,0,1]  (xor 2)
    r = dpp_add<0x141>(r);  // row_half_mirror      (xor 4)
    r = dpp_add<0x140>(r);  // row_mirror           (xor 8)
    r = dpp_add<0x142>(r);  // row_bcast15
    r = dpp_add<0x143>(r);  // row_bcast31 -> lane 63 holds the total
    return __int_as_float(__builtin_amdgcn_readlane(__float_as_int(r), 63));
}

__global__ __launch_bounds__(512)
void lstm_fused_kernel(const float* __restrict__ x,
                       const float* __restrict__ W_ih,
                       const float* __restrict__ b_ih,
                       const float* __restrict__ b_hh,
                       const float* __restrict__ fc_w,
                       const float* __restrict__ fc_b,
                       float* __restrict__ out)
{
    const int tid  = threadIdx.x;
    const int lane = tid & 63;
    const int w    = tid >> 6;                       // wave id 0..7
    const int b    = blockIdx.x * CH_PER_BLK + w;    // this wave's chain

    __shared__ int   sh_tstart[CH_PER_BLK];
    __shared__ float sh_pstar [CH_PER_BLK];

    const int k0 = lane;
    const int k1 = lane + 64;

    const float LOG2E  = 1.44269504088896340736f;
    const float L2E2   = 2.0f * LOG2E;

    // gate rows in 4H: i:[0,128) f:[128,256) g:[256,384) o:[384,512)
    // sigmoid(x) = rcp(1 + exp2(-x*log2e))  -> fold -log2e into w,b
    // tanh(x)    = 1 - 2*rcp(1 + exp2(2x*log2e)) -> fold 2*log2e into w,b
    const float wi0 = -LOG2E * W_ih[k0],       wi1 = -LOG2E * W_ih[k1];
    const float wg0 =  L2E2  * W_ih[256 + k0], wg1 =  L2E2  * W_ih[256 + k1];
    const float wo0 = -LOG2E * W_ih[384 + k0], wo1 = -LOG2E * W_ih[384 + k1];
    const float bi0 = -LOG2E * (b_ih[k0]       + b_hh[k0]);
    const float bi1 = -LOG2E * (b_ih[k1]       + b_hh[k1]);
    const float bg0 =  L2E2  * (b_ih[256 + k0] + b_hh[256 + k0]);
    const float bg1 =  L2E2  * (b_ih[256 + k1] + b_hh[256 + k1]);
    const float bo0 = -LOG2E * (b_ih[384 + k0] + b_hh[384 + k0]);
    const float bo1 = -LOG2E * (b_ih[384 + k1] + b_hh[384 + k1]);
    const float fw0 = fc_w[k0],  fw1 = fc_w[k1];
    const float fcb_lane = (lane == 0) ? fc_b[0] : 0.0f;   // folded pre-butterfly

    float s = x[b];                        // x[0, b, 0]; autonomous mode
    int   s_prev_bits = 0x7fc00000;        // NaN bits: never equals a real p
    int   t = 0;

    for (; t < T_STEPS; ++t) {
        // sigmoid(i), sigmoid(o): rcp(1+exp2(arg)), arg pre-negated+scaled
        const float si0 = fast_rcp(1.0f + fast_exp2(fmaf(s, wi0, bi0)));
        const float si1 = fast_rcp(1.0f + fast_exp2(fmaf(s, wi1, bi1)));
        const float so0 = fast_rcp(1.0f + fast_exp2(fmaf(s, wo0, bo0)));
        const float so1 = fast_rcp(1.0f + fast_exp2(fmaf(s, wo1, bo1)));
        // tanh(g): 1 - 2*rcp(1+exp2(arg)), arg pre-scaled by 2*log2e
        const float tg0 = 1.0f - 2.0f * fast_rcp(1.0f + fast_exp2(fmaf(s, wg0, bg0)));
        const float tg1 = 1.0f - 2.0f * fast_rcp(1.0f + fast_exp2(fmaf(s, wg1, bg1)));

        const float c0 = si0 * tg0;
        const float c1 = si1 * tg1;
        const float tc0 = 1.0f - 2.0f * fast_rcp(1.0f + fast_exp2(c0 * L2E2));
        const float tc1 = 1.0f - 2.0f * fast_rcp(1.0f + fast_exp2(c1 * L2E2));
        const float h0 = so0 * tc0;
        const float h1 = so1 * tc1;

        float r = fmaf(fmaxf(h0, 0.0f), fw0, fcb_lane);
        r = fmaf(fmaxf(h1, 0.0f), fw1, r);

        const float p = wave_sum64(r);         // wave-uniform, fc_b included
        if (lane == 0) out[t * BATCH + b] = p;

        const int p_bits = __float_as_int(p);
        s = p;
        if (p_bits == s_prev_bits) break;      // bitwise fixed point reached
        s_prev_bits = p_bits;
    }

    if (lane == 0) {
        sh_tstart[w] = (t < T_STEPS) ? (t + 1) : T_STEPS;
        sh_pstar[w]  = s;
    }
    __syncthreads();

    // Block-cooperative coalesced tail fill for this block's 8 columns.
    // tid -> (row = tid/8 + pass*64, col = tid%8): 8 consecutive lanes write
    // 32 B contiguous.
    const int col   = tid & (CH_PER_BLK - 1);
    const int row0  = tid >> 3;                       // 0..63
    const int base  = blockIdx.x * CH_PER_BLK;
    const int ts    = sh_tstart[col];
    const float ps  = sh_pstar[col];
    #pragma unroll
    for (int row = row0; row < T_STEPS; row += 64) {
        if (row >= ts) out[row * BATCH + base + col] = ps;
    }
}

extern "C" void kernel_launch(void* const* d_in, const int* in_sizes, int n_in,
                              void* d_out, int out_size, void* d_ws, size_t ws_size,
                              hipStream_t stream) {
    const float* x    = (const float*)d_in[0];   // (T, BATCH, 1)
    const float* W_ih = (const float*)d_in[1];   // (512, 1)
    // d_in[2] = W_hh — provably unused (h0 = 0)
    const float* b_ih = (const float*)d_in[3];   // (512,)
    const float* b_hh = (const float*)d_in[4];   // (512,)
    const float* fc_w = (const float*)d_in[5];   // (1, 128)
    const float* fc_b = (const float*)d_in[6];   // (1,)
    float* out = (float*)d_out;                  // (T, BATCH) fp32

    lstm_fused_kernel<<<NBLK, 512, 0, stream>>>(x, W_ih, b_ih, b_hh, fc_w, fc_b, out);
}